// Round 5
// baseline (200.993 us; speedup 1.0000x reference)
//
#include <hip/hip_runtime.h>
#include <stdint.h>

#define A_ 9
#define N_ANCH 90000
#define PRE_NMS 6000
#define POST_NMS 300
#define NMS_TH 0.7f
#define NBINS 4096
#define CAND_CAP 8192
#define MASK_W 94   /* ceil(6000/64) */

/* ---- workspace byte offsets ---- */
#define OFF_HIST   0u          /* 4096*4 = 16384  (zeroed) */
#define OFF_BINCNT 16384u      /* 4096*4 = 16384  (zeroed) */
#define OFF_SCAL   32768u      /* 256             (zeroed) */
#define OFF_SUF    33024u      /* 4096*4 = 16384 */
#define OFF_CAND   49408u      /* 8192*8 = 65536 */
#define OFF_ORDER  114944u     /* 6000*4 */
#define OFF_TSCORE 138944u     /* 6000*4 */
#define OFF_TBOX   162944u     /* 6000*16 */
#define OFF_MASK   258944u     /* 6000*94*8 = 4512000 */

typedef unsigned long long u64;
typedef unsigned int u32;

__device__ __forceinline__ int score_bin(float s) {
    int bin = (int)(s * (float)NBINS);
    return bin < 0 ? 0 : (bin > NBINS - 1 ? NBINS - 1 : bin);
}

/* 1) global score histogram */
__global__ void k_hist(const float* __restrict__ cls, int* __restrict__ hist) {
    int n = blockIdx.x * blockDim.x + threadIdx.x;
    if (n >= N_ANCH) return;
    float s = cls[(n / A_) * (2 * A_) + A_ + (n % A_)];
    atomicAdd(&hist[score_bin(s)], 1);
}

/* 2) suffix-scan histogram: sufAbove[b] = #keys in bins > b; find T and M */
__global__ void __launch_bounds__(256) k_scan(const int* __restrict__ hist,
                                              int* __restrict__ sufAbove,
                                              int* __restrict__ scal) {
    __shared__ int chunks[256];
    __shared__ int above[256];
    __shared__ int sufs[NBINS];
    __shared__ int Tsh;
    int t = threadIdx.x;
    int hl[16];
    int csum = 0;
#pragma unroll
    for (int k = 0; k < 16; ++k) { hl[k] = hist[t * 16 + k]; csum += hl[k]; }
    chunks[t] = csum;
    if (t == 0) Tsh = 0;
    __syncthreads();
    if (t == 0) {
        int acc = 0;
        for (int b = 255; b >= 0; --b) { above[b] = acc; acc += chunks[b]; }
    }
    __syncthreads();
    int acc = above[t];
    int best = -1;
#pragma unroll
    for (int k = 15; k >= 0; --k) {
        sufs[t * 16 + k] = acc;
        acc += hl[k];
        if (best < 0 && acc >= PRE_NMS) best = t * 16 + k;
    }
    if (best >= 0) atomicMax(&Tsh, best);
    __syncthreads();
#pragma unroll
    for (int k = 0; k < 16; ++k) sufAbove[t * 16 + k] = sufs[t * 16 + k];
    if (t == 0) {
        int T = Tsh;
        scal[0] = T;
        scal[1] = sufs[T] + hist[T];   /* M = total candidates (bins >= T) */
    }
}

/* 3) compact candidates into bin-segmented storage at their final rank range */
__global__ void k_compact(const float* __restrict__ cls,
                          const int* __restrict__ sufAbove,
                          const int* __restrict__ scal,
                          int* __restrict__ binCnt,
                          u64* __restrict__ cand) {
    int n = blockIdx.x * blockDim.x + threadIdx.x;
    if (n >= N_ANCH) return;
    float s = cls[(n / A_) * (2 * A_) + A_ + (n % A_)];
    int bin = score_bin(s);
    int T = scal[0];
    if (bin >= T) {
        int slot = atomicAdd(&binCnt[bin], 1);
        int p = sufAbove[bin] + slot;
        if (p < CAND_CAP) {
            u64 key = ((u64)__float_as_uint(s) << 32) | (u64)(0xFFFFFFFFu - (u32)n);
            cand[p] = key;
        }
    }
}

/* 4) exact rank = sufAbove[bin] + #{same-bin keys > ki}; decode+clip box at rank */
__global__ void __launch_bounds__(256) k_rank(const u64* __restrict__ cand,
                                              const int* __restrict__ hist,
                                              const int* __restrict__ sufAbove,
                                              const int* __restrict__ scal,
                                              const float* __restrict__ anchors,
                                              const float* __restrict__ bbox,
                                              const float* __restrict__ im_info,
                                              int* __restrict__ order,
                                              float* __restrict__ tscore,
                                              float* __restrict__ tb) {
#pragma clang fp contract(off)
    int i = blockIdx.x * 256 + threadIdx.x;
    int M = scal[1];
    if (M > CAND_CAP) M = CAND_CAP;
    if (i >= M) return;
    u64 ki = cand[i];
    float sc = __uint_as_float((u32)(ki >> 32));
    int bin = score_bin(sc);
    int base = sufAbove[bin];
    int len = hist[bin];
    int end = base + len;
    if (end > CAND_CAP) end = CAND_CAP;
    int rank = base;
    for (int j = base; j < end; ++j)
        rank += (cand[j] > ki) ? 1 : 0;
    if (rank >= PRE_NMS) return;

    int n = (int)(0xFFFFFFFFu - (u32)(ki & 0xFFFFFFFFull));
    order[rank] = n;
    tscore[rank] = sc;

    int hw = n / A_, a = n % A_;
    const float* an = anchors + (size_t)n * 4;
    const float* d  = bbox + (size_t)hw * (4 * A_) + a * 4;
    float w  = an[2] - an[0] + 1.0f;
    float h  = an[3] - an[1] + 1.0f;
    float cx = an[0] + 0.5f * w;
    float cy = an[1] + 0.5f * h;
    float pcx = d[0] * w + cx;
    float pcy = d[1] * h + cy;
    float pw  = expf(d[2]) * w;
    float ph  = expf(d[3]) * h;
    float x1 = pcx - 0.5f * pw;
    float y1 = pcy - 0.5f * ph;
    float x2 = pcx + 0.5f * pw;
    float y2 = pcy + 0.5f * ph;
    float im_h = im_info[0], im_w = im_info[1];
    x1 = fminf(fmaxf(x1, 0.0f), im_w - 1.0f);
    y1 = fminf(fmaxf(y1, 0.0f), im_h - 1.0f);
    x2 = fminf(fmaxf(x2, 0.0f), im_w - 1.0f);
    y2 = fminf(fmaxf(y2, 0.0f), im_h - 1.0f);
    tb[rank * 4 + 0] = x1;
    tb[rank * 4 + 1] = y1;
    tb[rank * 4 + 2] = x2;
    tb[rank * 4 + 3] = y2;
}

/* 5) pairwise suppression bitmask, upper-triangle blocks only */
__global__ void __launch_bounds__(64) k_mask(const float* __restrict__ tb,
                                             u64* __restrict__ mask) {
#pragma clang fp contract(off)
    int cb = blockIdx.x, rb = blockIdx.y;
    if (cb < rb) return;           /* lower-triangle words never affect decisions */
    __shared__ float cbx[64][4];
    __shared__ float car[64];
    int t = threadIdx.x;
    int j0 = cb * 64;
    int jj = j0 + t;
    if (jj < PRE_NMS) {
        float bx1 = tb[jj * 4 + 0], by1 = tb[jj * 4 + 1];
        float bx2 = tb[jj * 4 + 2], by2 = tb[jj * 4 + 3];
        cbx[t][0] = bx1; cbx[t][1] = by1; cbx[t][2] = bx2; cbx[t][3] = by2;
        car[t] = (bx2 - bx1 + 1.0f) * (by2 - by1 + 1.0f);
    } else {
        cbx[t][0] = 0; cbx[t][1] = 0; cbx[t][2] = -2; cbx[t][3] = -2;
        car[t] = 1.0f;
    }
    __syncthreads();
    int row = rb * 64 + t;
    if (row >= PRE_NMS) return;
    float x1 = tb[row * 4 + 0], y1 = tb[row * 4 + 1];
    float x2 = tb[row * 4 + 2], y2 = tb[row * 4 + 3];
    float ai = (x2 - x1 + 1.0f) * (y2 - y1 + 1.0f);
    u64 bits = 0;
    for (int c = 0; c < 64; ++c) {
        int j = j0 + c;
        if (j > row && j < PRE_NMS) {
            float xx1 = fmaxf(x1, cbx[c][0]);
            float yy1 = fmaxf(y1, cbx[c][1]);
            float xx2 = fminf(x2, cbx[c][2]);
            float yy2 = fminf(y2, cbx[c][3]);
            float iw = fmaxf(xx2 - xx1 + 1.0f, 0.0f);
            float ih = fmaxf(yy2 - yy1 + 1.0f, 0.0f);
            float inter = iw * ih;
            float iou = inter / (ai + car[c] - inter);
            if (iou > NMS_TH) bits |= (1ull << c);
        }
    }
    mask[(size_t)row * MASK_W + cb] = bits;
}

/* 6) greedy reduce, keep-driven: per 64-row chunk, find-first-zero visits ONLY
      kept rows; diag word broadcast via v_readlane (scalar, no LDS); kept rows'
      full mask rows loaded into a 4-deep static register ring, OR-ed into the
      distributed remv bitmap at chunk end (one latency stall per chunk). */
__global__ void __launch_bounds__(256) k_reduce_out(const u64* __restrict__ mask,
                                                    const int* __restrict__ order,
                                                    const float* __restrict__ tb,
                                                    const float* __restrict__ tscore,
                                                    const float* __restrict__ trans,
                                                    float* __restrict__ out) {
    __shared__ int keep_s[POST_NMS];
    if (threadIdx.x < 64) {
        int lane = threadIdx.x;
        bool l2 = lane < (MASK_W - 64);
        u64 remv0 = 0, remv1 = 0;                 /* lane l owns words l, 64+l */
        u64 pa0 = 0, pa1 = 0, pb0 = 0, pb1 = 0;   /* deferred-OR ring slots */
        u64 pc0 = 0, pc1 = 0, pd0 = 0, pd1 = 0;
        int kr = 0;
        int cnt = 0;
        /* prefetch chunk-0 diagonal words: lane l -> mask[l][0] */
        u64 dwc = mask[(size_t)lane * MASK_W + 0];
        u64 cur = 0;                              /* remv word for current chunk (uniform) */
        for (int c = 0; c < MASK_W; ++c) {
            /* prefetch next chunk's diagonal words */
            u64 dwn = 0;
            int nc = c + 1;
            if (nc < MASK_W) {
                int rn = nc * 64 + lane;
                if (rn < PRE_NMS) dwn = mask[(size_t)rn * MASK_W + nc];
            }
            int nrows = PRE_NMS - c * 64; if (nrows > 64) nrows = 64;
            u64 vm = (nrows >= 64) ? ~0ull : ((1ull << nrows) - 1ull);
            u64 freeb = (~cur) & vm;
            while (freeb) {
                int b = __builtin_ctzll(freeb);
                int bs = __builtin_amdgcn_readfirstlane(b);
                int i = c * 64 + bs;
                if (lane == 0) keep_s[cnt] = i;
                cnt++;
                /* broadcast kept row's diagonal word from lane bs (scalar readlane) */
                u32 dlo, dhi;
                asm("v_readlane_b32 %0, %1, %2" : "=s"(dlo) : "v"((u32)dwc), "s"(bs));
                asm("v_readlane_b32 %0, %1, %2" : "=s"(dhi) : "v"((u32)(dwc >> 32)), "s"(bs));
                u64 dwb = ((u64)dhi << 32) | (u64)dlo;
                cur |= dwb | (1ull << bs);
                freeb = (~cur) & vm;
                /* load kept row's full mask row into ring slot (OR deferred) */
                const u64* rowp = mask + (size_t)i * MASK_W;
                int sl = kr & 3; kr++;
                if (sl == 0)      { remv0 |= pa0; remv1 |= pa1; pa0 = rowp[lane]; pa1 = l2 ? rowp[64 + lane] : 0; }
                else if (sl == 1) { remv0 |= pb0; remv1 |= pb1; pb0 = rowp[lane]; pb1 = l2 ? rowp[64 + lane] : 0; }
                else if (sl == 2) { remv0 |= pc0; remv1 |= pc1; pc0 = rowp[lane]; pc1 = l2 ? rowp[64 + lane] : 0; }
                else              { remv0 |= pd0; remv1 |= pd1; pd0 = rowp[lane]; pd1 = l2 ? rowp[64 + lane] : 0; }
                if (cnt == POST_NMS) break;
            }
            if (cnt == POST_NMS) break;
            /* drain ring, then fetch next chunk's remv word via readlane */
            remv0 |= pa0 | pb0 | pc0 | pd0;  pa0 = pb0 = pc0 = pd0 = 0;
            remv1 |= pa1 | pb1 | pc1 | pd1;  pa1 = pb1 = pc1 = pd1 = 0;
            dwc = dwn;
            if (nc < MASK_W) {
                u32 clo, chi;
                if (nc < 64) {
                    int ncs = __builtin_amdgcn_readfirstlane(nc);
                    asm("v_readlane_b32 %0, %1, %2" : "=s"(clo) : "v"((u32)remv0), "s"(ncs));
                    asm("v_readlane_b32 %0, %1, %2" : "=s"(chi) : "v"((u32)(remv0 >> 32)), "s"(ncs));
                } else {
                    int ncs = __builtin_amdgcn_readfirstlane(nc - 64);
                    asm("v_readlane_b32 %0, %1, %2" : "=s"(clo) : "v"((u32)remv1), "s"(ncs));
                    asm("v_readlane_b32 %0, %1, %2" : "=s"(chi) : "v"((u32)(remv1 >> 32)), "s"(ncs));
                }
                cur = ((u64)chi << 32) | (u64)clo;
            }
        }
        for (int r = cnt + lane; r < POST_NMS; r += 64) keep_s[r] = 0;
    }
    __syncthreads();
    for (int row = threadIdx.x; row < POST_NMS; row += 256) {
        int r = keep_s[row];
        int n = order[r];
        out[row * 5 + 0] = 0.0f;
        out[row * 5 + 1] = tb[r * 4 + 0];
        out[row * 5 + 2] = tb[r * 4 + 1];
        out[row * 5 + 3] = tb[r * 4 + 2];
        out[row * 5 + 4] = tb[r * 4 + 3];
        out[POST_NMS * 5 + row] = tscore[r];
        int hw = n / A_, a = n % A_;
        const float* tp = trans + (size_t)hw * (6 * A_) + a * 6;
#pragma unroll
        for (int c = 0; c < 6; ++c)
            out[POST_NMS * 6 + row * 6 + c] = tp[c];
    }
}

extern "C" void kernel_launch(void* const* d_in, const int* in_sizes, int n_in,
                              void* d_out, int out_size, void* d_ws, size_t ws_size,
                              hipStream_t stream) {
    const float* anchors = (const float*)d_in[0];
    const float* cls     = (const float*)d_in[1];
    const float* bbox    = (const float*)d_in[2];
    const float* trans   = (const float*)d_in[3];
    const float* im_info = (const float*)d_in[4];
    float* out = (float*)d_out;
    char* ws = (char*)d_ws;

    int*   hist   = (int*)(ws + OFF_HIST);
    int*   binCnt = (int*)(ws + OFF_BINCNT);
    int*   scal   = (int*)(ws + OFF_SCAL);
    int*   suf    = (int*)(ws + OFF_SUF);
    u64*   cand   = (u64*)(ws + OFF_CAND);
    int*   order  = (int*)(ws + OFF_ORDER);
    float* tscore = (float*)(ws + OFF_TSCORE);
    float* tb     = (float*)(ws + OFF_TBOX);
    u64*   mask   = (u64*)(ws + OFF_MASK);

    /* zero hist + binCnt + scal each call */
    hipMemsetAsync(ws + OFF_HIST, 0, OFF_SUF - OFF_HIST, stream);

    int nb = (N_ANCH + 255) / 256;
    k_hist<<<nb, 256, 0, stream>>>(cls, hist);
    k_scan<<<1, 256, 0, stream>>>(hist, suf, scal);
    k_compact<<<nb, 256, 0, stream>>>(cls, suf, scal, binCnt, cand);
    k_rank<<<CAND_CAP / 256, 256, 0, stream>>>(cand, hist, suf, scal,
                                               anchors, bbox, im_info,
                                               order, tscore, tb);
    dim3 mg(MASK_W, MASK_W);
    k_mask<<<mg, 64, 0, stream>>>(tb, mask);
    k_reduce_out<<<1, 256, 0, stream>>>(mask, order, tb, tscore, trans, out);
}

// Round 6
// 132.544 us; speedup vs baseline: 1.5164x; 1.5164x over previous
//
#include <hip/hip_runtime.h>
#include <stdint.h>

#define A_ 9
#define N_ANCH 90000
#define PRE_NMS 6000
#define POST_NMS 300
#define NMS_TH 0.7f
#define NBINS 4096
#define CAND_CAP 8192
#define MASK_W 94   /* ceil(6000/64) */

/* ---- workspace byte offsets ---- */
#define OFF_HIST   0u          /* 4096*4 = 16384  (zeroed) */
#define OFF_BINCNT 16384u      /* 4096*4 = 16384  (zeroed) */
#define OFF_SCAL   32768u      /* 256             (zeroed) */
#define OFF_SUF    33024u      /* 4096*4 = 16384 */
#define OFF_CAND   49408u      /* 8192*8 = 65536 */
#define OFF_ORDER  114944u     /* 6000*4 */
#define OFF_TSCORE 138944u     /* 6000*4 */
#define OFF_TBOX   162944u     /* 6000*16 */
#define OFF_MASK   258944u     /* 6000*94*8 = 4512000 */

typedef unsigned long long u64;
typedef unsigned int u32;

__device__ __forceinline__ int score_bin(float s) {
    int bin = (int)(s * (float)NBINS);
    return bin < 0 ? 0 : (bin > NBINS - 1 ? NBINS - 1 : bin);
}

/* 1) global score histogram */
__global__ void k_hist(const float* __restrict__ cls, int* __restrict__ hist) {
    int n = blockIdx.x * blockDim.x + threadIdx.x;
    if (n >= N_ANCH) return;
    float s = cls[(n / A_) * (2 * A_) + A_ + (n % A_)];
    atomicAdd(&hist[score_bin(s)], 1);
}

/* 2) suffix-scan histogram: sufAbove[b] = #keys in bins > b; find T and M */
__global__ void __launch_bounds__(256) k_scan(const int* __restrict__ hist,
                                              int* __restrict__ sufAbove,
                                              int* __restrict__ scal) {
    __shared__ int chunks[256];
    __shared__ int above[256];
    __shared__ int sufs[NBINS];
    __shared__ int Tsh;
    int t = threadIdx.x;
    int hl[16];
    int csum = 0;
#pragma unroll
    for (int k = 0; k < 16; ++k) { hl[k] = hist[t * 16 + k]; csum += hl[k]; }
    chunks[t] = csum;
    if (t == 0) Tsh = 0;
    __syncthreads();
    if (t == 0) {
        int acc = 0;
        for (int b = 255; b >= 0; --b) { above[b] = acc; acc += chunks[b]; }
    }
    __syncthreads();
    int acc = above[t];
    int best = -1;
#pragma unroll
    for (int k = 15; k >= 0; --k) {
        sufs[t * 16 + k] = acc;
        acc += hl[k];
        if (best < 0 && acc >= PRE_NMS) best = t * 16 + k;
    }
    if (best >= 0) atomicMax(&Tsh, best);
    __syncthreads();
#pragma unroll
    for (int k = 0; k < 16; ++k) sufAbove[t * 16 + k] = sufs[t * 16 + k];
    if (t == 0) {
        int T = Tsh;
        scal[0] = T;
        scal[1] = sufs[T] + hist[T];   /* M = total candidates (bins >= T) */
    }
}

/* 3) compact candidates into bin-segmented storage at their final rank range */
__global__ void k_compact(const float* __restrict__ cls,
                          const int* __restrict__ sufAbove,
                          const int* __restrict__ scal,
                          int* __restrict__ binCnt,
                          u64* __restrict__ cand) {
    int n = blockIdx.x * blockDim.x + threadIdx.x;
    if (n >= N_ANCH) return;
    float s = cls[(n / A_) * (2 * A_) + A_ + (n % A_)];
    int bin = score_bin(s);
    int T = scal[0];
    if (bin >= T) {
        int slot = atomicAdd(&binCnt[bin], 1);
        int p = sufAbove[bin] + slot;
        if (p < CAND_CAP) {
            u64 key = ((u64)__float_as_uint(s) << 32) | (u64)(0xFFFFFFFFu - (u32)n);
            cand[p] = key;
        }
    }
}

/* 4) exact rank = sufAbove[bin] + #{same-bin keys > ki}; decode+clip box at rank */
__global__ void __launch_bounds__(256) k_rank(const u64* __restrict__ cand,
                                              const int* __restrict__ hist,
                                              const int* __restrict__ sufAbove,
                                              const int* __restrict__ scal,
                                              const float* __restrict__ anchors,
                                              const float* __restrict__ bbox,
                                              const float* __restrict__ im_info,
                                              int* __restrict__ order,
                                              float* __restrict__ tscore,
                                              float* __restrict__ tb) {
#pragma clang fp contract(off)
    int i = blockIdx.x * 256 + threadIdx.x;
    int M = scal[1];
    if (M > CAND_CAP) M = CAND_CAP;
    if (i >= M) return;
    u64 ki = cand[i];
    float sc = __uint_as_float((u32)(ki >> 32));
    int bin = score_bin(sc);
    int base = sufAbove[bin];
    int len = hist[bin];
    int end = base + len;
    if (end > CAND_CAP) end = CAND_CAP;
    int rank = base;
    for (int j = base; j < end; ++j)
        rank += (cand[j] > ki) ? 1 : 0;
    if (rank >= PRE_NMS) return;

    int n = (int)(0xFFFFFFFFu - (u32)(ki & 0xFFFFFFFFull));
    order[rank] = n;
    tscore[rank] = sc;

    int hw = n / A_, a = n % A_;
    const float* an = anchors + (size_t)n * 4;
    const float* d  = bbox + (size_t)hw * (4 * A_) + a * 4;
    float w  = an[2] - an[0] + 1.0f;
    float h  = an[3] - an[1] + 1.0f;
    float cx = an[0] + 0.5f * w;
    float cy = an[1] + 0.5f * h;
    float pcx = d[0] * w + cx;
    float pcy = d[1] * h + cy;
    float pw  = expf(d[2]) * w;
    float ph  = expf(d[3]) * h;
    float x1 = pcx - 0.5f * pw;
    float y1 = pcy - 0.5f * ph;
    float x2 = pcx + 0.5f * pw;
    float y2 = pcy + 0.5f * ph;
    float im_h = im_info[0], im_w = im_info[1];
    x1 = fminf(fmaxf(x1, 0.0f), im_w - 1.0f);
    y1 = fminf(fmaxf(y1, 0.0f), im_h - 1.0f);
    x2 = fminf(fmaxf(x2, 0.0f), im_w - 1.0f);
    y2 = fminf(fmaxf(y2, 0.0f), im_h - 1.0f);
    tb[rank * 4 + 0] = x1;
    tb[rank * 4 + 1] = y1;
    tb[rank * 4 + 2] = x2;
    tb[rank * 4 + 3] = y2;
}

/* 5) pairwise suppression bitmask, upper-triangle blocks only */
__global__ void __launch_bounds__(64) k_mask(const float* __restrict__ tb,
                                             u64* __restrict__ mask) {
#pragma clang fp contract(off)
    int cb = blockIdx.x, rb = blockIdx.y;
    if (cb < rb) return;           /* lower-triangle words are never read */
    __shared__ float cbx[64][4];
    __shared__ float car[64];
    int t = threadIdx.x;
    int j0 = cb * 64;
    int jj = j0 + t;
    if (jj < PRE_NMS) {
        float bx1 = tb[jj * 4 + 0], by1 = tb[jj * 4 + 1];
        float bx2 = tb[jj * 4 + 2], by2 = tb[jj * 4 + 3];
        cbx[t][0] = bx1; cbx[t][1] = by1; cbx[t][2] = bx2; cbx[t][3] = by2;
        car[t] = (bx2 - bx1 + 1.0f) * (by2 - by1 + 1.0f);
    } else {
        cbx[t][0] = 0; cbx[t][1] = 0; cbx[t][2] = -2; cbx[t][3] = -2;
        car[t] = 1.0f;
    }
    __syncthreads();
    int row = rb * 64 + t;
    if (row >= PRE_NMS) return;
    float x1 = tb[row * 4 + 0], y1 = tb[row * 4 + 1];
    float x2 = tb[row * 4 + 2], y2 = tb[row * 4 + 3];
    float ai = (x2 - x1 + 1.0f) * (y2 - y1 + 1.0f);
    u64 bits = 0;
    for (int c = 0; c < 64; ++c) {
        int j = j0 + c;
        if (j > row && j < PRE_NMS) {
            float xx1 = fmaxf(x1, cbx[c][0]);
            float yy1 = fmaxf(y1, cbx[c][1]);
            float xx2 = fminf(x2, cbx[c][2]);
            float yy2 = fminf(y2, cbx[c][3]);
            float iw = fmaxf(xx2 - xx1 + 1.0f, 0.0f);
            float ih = fmaxf(yy2 - yy1 + 1.0f, 0.0f);
            float inter = iw * ih;
            float iou = inter / (ai + car[c] - inter);
            if (iou > NMS_TH) bits |= (1ull << c);
        }
    }
    mask[(size_t)row * MASK_W + cb] = bits;
}

/* 6) greedy reduce, zero memory ops in the per-keep chain:
      - per 64-row chunk: decisions via find-first-zero on uniform `cur`,
        diagonal words prefetched one chunk ahead, broadcast by v_readlane.
      - kept indices recorded in 5 statically-indexed VGPRs (lane k&63, slot k>>6).
      - at chunk transition: cur(next) = OR over kept rows' mask word `nc`,
        gathered in parallel (<=5 loads/lane, one latency) + shfl_xor OR-butterfly. */
__global__ void __launch_bounds__(256) k_reduce_out(const u64* __restrict__ mask,
                                                    const int* __restrict__ order,
                                                    const float* __restrict__ tb,
                                                    const float* __restrict__ tscore,
                                                    const float* __restrict__ trans,
                                                    float* __restrict__ out) {
    __shared__ int keep_s[POST_NMS];
    if (threadIdx.x < 64) {
        int lane = threadIdx.x;
        int k0 = 0, k1 = 0, k2 = 0, k3 = 0, k4 = 0;   /* distributed keep list */
        int cnt = 0;
        u64 dwc = mask[(size_t)lane * MASK_W + 0];    /* chunk-0 diagonal words */
        u64 cur = 0;
        for (int c = 0; c < MASK_W; ++c) {
            int nc = c + 1;
            u64 dwn = 0;
            if (nc < MASK_W) {
                int rn = nc * 64 + lane;
                if (rn < PRE_NMS) dwn = mask[(size_t)rn * MASK_W + nc];
            }
            int nrows = PRE_NMS - c * 64; if (nrows > 64) nrows = 64;
            u64 vm = (nrows >= 64) ? ~0ull : ((1ull << nrows) - 1ull);
            u64 freeb = (~cur) & vm;
            while (freeb) {
                int b = __builtin_ctzll(freeb);
                int bs = __builtin_amdgcn_readfirstlane(b);
                int i = c * 64 + bs;
                int s = cnt >> 6;
                if (lane == (cnt & 63)) {
                    if (s == 0) k0 = i; else if (s == 1) k1 = i;
                    else if (s == 2) k2 = i; else if (s == 3) k3 = i; else k4 = i;
                }
                cnt++;
                u32 dlo, dhi;
                asm("v_readlane_b32 %0, %1, %2" : "=s"(dlo) : "v"((u32)dwc), "s"(bs));
                asm("v_readlane_b32 %0, %1, %2" : "=s"(dhi) : "v"((u32)(dwc >> 32)), "s"(bs));
                cur |= (((u64)dhi << 32) | (u64)dlo) | (1ull << bs);
                if (cnt == POST_NMS) break;
                freeb = (~cur) & vm;
            }
            if (cnt == POST_NMS || nc >= MASK_W) break;
            /* chunk transition: gather word nc of all kept rows, OR-reduce */
            u64 acc = 0;
            if (0 * 64 + lane < cnt) acc |= mask[(size_t)k0 * MASK_W + nc];
            if (1 * 64 + lane < cnt) acc |= mask[(size_t)k1 * MASK_W + nc];
            if (2 * 64 + lane < cnt) acc |= mask[(size_t)k2 * MASK_W + nc];
            if (3 * 64 + lane < cnt) acc |= mask[(size_t)k3 * MASK_W + nc];
            if (4 * 64 + lane < cnt) acc |= mask[(size_t)k4 * MASK_W + nc];
#pragma unroll
            for (int m = 32; m >= 1; m >>= 1)
                acc |= (u64)__shfl_xor((unsigned long long)acc, m, 64);
            cur = acc;
            dwc = dwn;
        }
        if (0 * 64 + lane < cnt) keep_s[0 * 64 + lane] = k0;
        if (1 * 64 + lane < cnt) keep_s[1 * 64 + lane] = k1;
        if (2 * 64 + lane < cnt) keep_s[2 * 64 + lane] = k2;
        if (3 * 64 + lane < cnt) keep_s[3 * 64 + lane] = k3;
        if (4 * 64 + lane < cnt) keep_s[4 * 64 + lane] = k4;
        for (int r = cnt + lane; r < POST_NMS; r += 64) keep_s[r] = 0;
    }
    __syncthreads();
    for (int row = threadIdx.x; row < POST_NMS; row += 256) {
        int r = keep_s[row];
        int n = order[r];
        out[row * 5 + 0] = 0.0f;
        out[row * 5 + 1] = tb[r * 4 + 0];
        out[row * 5 + 2] = tb[r * 4 + 1];
        out[row * 5 + 3] = tb[r * 4 + 2];
        out[row * 5 + 4] = tb[r * 4 + 3];
        out[POST_NMS * 5 + row] = tscore[r];
        int hw = n / A_, a = n % A_;
        const float* tp = trans + (size_t)hw * (6 * A_) + a * 6;
#pragma unroll
        for (int c = 0; c < 6; ++c)
            out[POST_NMS * 6 + row * 6 + c] = tp[c];
    }
}

extern "C" void kernel_launch(void* const* d_in, const int* in_sizes, int n_in,
                              void* d_out, int out_size, void* d_ws, size_t ws_size,
                              hipStream_t stream) {
    const float* anchors = (const float*)d_in[0];
    const float* cls     = (const float*)d_in[1];
    const float* bbox    = (const float*)d_in[2];
    const float* trans   = (const float*)d_in[3];
    const float* im_info = (const float*)d_in[4];
    float* out = (float*)d_out;
    char* ws = (char*)d_ws;

    int*   hist   = (int*)(ws + OFF_HIST);
    int*   binCnt = (int*)(ws + OFF_BINCNT);
    int*   scal   = (int*)(ws + OFF_SCAL);
    int*   suf    = (int*)(ws + OFF_SUF);
    u64*   cand   = (u64*)(ws + OFF_CAND);
    int*   order  = (int*)(ws + OFF_ORDER);
    float* tscore = (float*)(ws + OFF_TSCORE);
    float* tb     = (float*)(ws + OFF_TBOX);
    u64*   mask   = (u64*)(ws + OFF_MASK);

    /* zero hist + binCnt + scal each call */
    hipMemsetAsync(ws + OFF_HIST, 0, OFF_SUF - OFF_HIST, stream);

    int nb = (N_ANCH + 255) / 256;
    k_hist<<<nb, 256, 0, stream>>>(cls, hist);
    k_scan<<<1, 256, 0, stream>>>(hist, suf, scal);
    k_compact<<<nb, 256, 0, stream>>>(cls, suf, scal, binCnt, cand);
    k_rank<<<CAND_CAP / 256, 256, 0, stream>>>(cand, hist, suf, scal,
                                               anchors, bbox, im_info,
                                               order, tscore, tb);
    dim3 mg(MASK_W, MASK_W);
    k_mask<<<mg, 64, 0, stream>>>(tb, mask);
    k_reduce_out<<<1, 256, 0, stream>>>(mask, order, tb, tscore, trans, out);
}

// Round 7
// 84.294 us; speedup vs baseline: 2.3844x; 1.5724x over previous
//
#include <hip/hip_runtime.h>
#include <stdint.h>

#define A_ 9
#define N_ANCH 90000
#define PRE_NMS 6000
#define POST_NMS 300
#define NMS_TH 0.7f
#define NBINS 4096
#define CAND_CAP 8192
#define MASK_W 94   /* ceil(6000/64) */

/* ---- workspace byte offsets ---- */
#define OFF_HIST   0u          /* 4096*4 = 16384  (zeroed) */
#define OFF_BINCNT 16384u      /* 4096*4 = 16384  (zeroed) */
#define OFF_SCAL   32768u      /* 256             (zeroed) */
#define OFF_SUF    33024u      /* 4096*4 = 16384 */
#define OFF_CAND   49408u      /* 8192*8 = 65536 */
#define OFF_ORDER  114944u     /* 6000*4 */
#define OFF_TSCORE 138944u     /* 6000*4 */
#define OFF_TBOX   162944u     /* 6000*16 */
#define OFF_MASK   258944u     /* 6000*94*8 = 4512000 */

typedef unsigned long long u64;
typedef unsigned int u32;

__device__ __forceinline__ int score_bin(float s) {
    int bin = (int)(s * (float)NBINS);
    return bin < 0 ? 0 : (bin > NBINS - 1 ? NBINS - 1 : bin);
}

/* 1) global score histogram */
__global__ void k_hist(const float* __restrict__ cls, int* __restrict__ hist) {
    int n = blockIdx.x * blockDim.x + threadIdx.x;
    if (n >= N_ANCH) return;
    float s = cls[(n / A_) * (2 * A_) + A_ + (n % A_)];
    atomicAdd(&hist[score_bin(s)], 1);
}

/* 2) suffix-scan histogram: sufAbove[b] = #keys in bins > b; find T and M */
__global__ void __launch_bounds__(256) k_scan(const int* __restrict__ hist,
                                              int* __restrict__ sufAbove,
                                              int* __restrict__ scal) {
    __shared__ int chunks[256];
    __shared__ int above[256];
    __shared__ int sufs[NBINS];
    __shared__ int Tsh;
    int t = threadIdx.x;
    int hl[16];
    int csum = 0;
#pragma unroll
    for (int k = 0; k < 16; ++k) { hl[k] = hist[t * 16 + k]; csum += hl[k]; }
    chunks[t] = csum;
    if (t == 0) Tsh = 0;
    __syncthreads();
    if (t == 0) {
        int acc = 0;
        for (int b = 255; b >= 0; --b) { above[b] = acc; acc += chunks[b]; }
    }
    __syncthreads();
    int acc = above[t];
    int best = -1;
#pragma unroll
    for (int k = 15; k >= 0; --k) {
        sufs[t * 16 + k] = acc;
        acc += hl[k];
        if (best < 0 && acc >= PRE_NMS) best = t * 16 + k;
    }
    if (best >= 0) atomicMax(&Tsh, best);
    __syncthreads();
#pragma unroll
    for (int k = 0; k < 16; ++k) sufAbove[t * 16 + k] = sufs[t * 16 + k];
    if (t == 0) {
        int T = Tsh;
        scal[0] = T;
        scal[1] = sufs[T] + hist[T];   /* M = total candidates (bins >= T) */
    }
}

/* 3) compact candidates into bin-segmented storage at their final rank range */
__global__ void k_compact(const float* __restrict__ cls,
                          const int* __restrict__ sufAbove,
                          const int* __restrict__ scal,
                          int* __restrict__ binCnt,
                          u64* __restrict__ cand) {
    int n = blockIdx.x * blockDim.x + threadIdx.x;
    if (n >= N_ANCH) return;
    float s = cls[(n / A_) * (2 * A_) + A_ + (n % A_)];
    int bin = score_bin(s);
    int T = scal[0];
    if (bin >= T) {
        int slot = atomicAdd(&binCnt[bin], 1);
        int p = sufAbove[bin] + slot;
        if (p < CAND_CAP) {
            u64 key = ((u64)__float_as_uint(s) << 32) | (u64)(0xFFFFFFFFu - (u32)n);
            cand[p] = key;
        }
    }
}

/* 4) exact rank = sufAbove[bin] + #{same-bin keys > ki}; decode+clip box at rank */
__global__ void __launch_bounds__(256) k_rank(const u64* __restrict__ cand,
                                              const int* __restrict__ hist,
                                              const int* __restrict__ sufAbove,
                                              const int* __restrict__ scal,
                                              const float* __restrict__ anchors,
                                              const float* __restrict__ bbox,
                                              const float* __restrict__ im_info,
                                              int* __restrict__ order,
                                              float* __restrict__ tscore,
                                              float* __restrict__ tb) {
#pragma clang fp contract(off)
    int i = blockIdx.x * 256 + threadIdx.x;
    int M = scal[1];
    if (M > CAND_CAP) M = CAND_CAP;
    if (i >= M) return;
    u64 ki = cand[i];
    float sc = __uint_as_float((u32)(ki >> 32));
    int bin = score_bin(sc);
    int base = sufAbove[bin];
    int len = hist[bin];
    int end = base + len;
    if (end > CAND_CAP) end = CAND_CAP;
    int rank = base;
    for (int j = base; j < end; ++j)
        rank += (cand[j] > ki) ? 1 : 0;
    if (rank >= PRE_NMS) return;

    int n = (int)(0xFFFFFFFFu - (u32)(ki & 0xFFFFFFFFull));
    order[rank] = n;
    tscore[rank] = sc;

    int hw = n / A_, a = n % A_;
    const float* an = anchors + (size_t)n * 4;
    const float* d  = bbox + (size_t)hw * (4 * A_) + a * 4;
    float w  = an[2] - an[0] + 1.0f;
    float h  = an[3] - an[1] + 1.0f;
    float cx = an[0] + 0.5f * w;
    float cy = an[1] + 0.5f * h;
    float pcx = d[0] * w + cx;
    float pcy = d[1] * h + cy;
    float pw  = expf(d[2]) * w;
    float ph  = expf(d[3]) * h;
    float x1 = pcx - 0.5f * pw;
    float y1 = pcy - 0.5f * ph;
    float x2 = pcx + 0.5f * pw;
    float y2 = pcy + 0.5f * ph;
    float im_h = im_info[0], im_w = im_info[1];
    x1 = fminf(fmaxf(x1, 0.0f), im_w - 1.0f);
    y1 = fminf(fmaxf(y1, 0.0f), im_h - 1.0f);
    x2 = fminf(fmaxf(x2, 0.0f), im_w - 1.0f);
    y2 = fminf(fmaxf(y2, 0.0f), im_h - 1.0f);
    tb[rank * 4 + 0] = x1;
    tb[rank * 4 + 1] = y1;
    tb[rank * 4 + 2] = x2;
    tb[rank * 4 + 3] = y2;
}

/* 5) pairwise suppression bitmask, upper-triangle blocks only */
__global__ void __launch_bounds__(64) k_mask(const float* __restrict__ tb,
                                             u64* __restrict__ mask) {
#pragma clang fp contract(off)
    int cb = blockIdx.x, rb = blockIdx.y;
    if (cb < rb) return;           /* lower-triangle words are never read */
    __shared__ float cbx[64][4];
    __shared__ float car[64];
    int t = threadIdx.x;
    int j0 = cb * 64;
    int jj = j0 + t;
    if (jj < PRE_NMS) {
        float bx1 = tb[jj * 4 + 0], by1 = tb[jj * 4 + 1];
        float bx2 = tb[jj * 4 + 2], by2 = tb[jj * 4 + 3];
        cbx[t][0] = bx1; cbx[t][1] = by1; cbx[t][2] = bx2; cbx[t][3] = by2;
        car[t] = (bx2 - bx1 + 1.0f) * (by2 - by1 + 1.0f);
    } else {
        cbx[t][0] = 0; cbx[t][1] = 0; cbx[t][2] = -2; cbx[t][3] = -2;
        car[t] = 1.0f;
    }
    __syncthreads();
    int row = rb * 64 + t;
    if (row >= PRE_NMS) return;
    float x1 = tb[row * 4 + 0], y1 = tb[row * 4 + 1];
    float x2 = tb[row * 4 + 2], y2 = tb[row * 4 + 3];
    float ai = (x2 - x1 + 1.0f) * (y2 - y1 + 1.0f);
    u64 bits = 0;
    for (int c = 0; c < 64; ++c) {
        int j = j0 + c;
        if (j > row && j < PRE_NMS) {
            float xx1 = fmaxf(x1, cbx[c][0]);
            float yy1 = fmaxf(y1, cbx[c][1]);
            float xx2 = fminf(x2, cbx[c][2]);
            float yy2 = fminf(y2, cbx[c][3]);
            float iw = fmaxf(xx2 - xx1 + 1.0f, 0.0f);
            float ih = fmaxf(yy2 - yy1 + 1.0f, 0.0f);
            float inter = iw * ih;
            float iou = inter / (ai + car[c] - inter);
            if (iou > NMS_TH) bits |= (1ull << c);
        }
    }
    mask[(size_t)row * MASK_W + cb] = bits;
}

/* 6) greedy reduce with a FULLY SCALAR per-keep chain:
      cur/freeb/cnt/keptw live in SGPRs (s_ff1_i32_b64 + s_or_b64); the only
      VALU per keep is 2x v_readlane of the prefetched diag word. Keeps are
      recorded in keptw and written to keep_s once per chunk (vector epilogue,
      positions ascend naturally). Chunk transition: gather word nc of all
      kept rows (<=5 coalesced loads/lane from keep_s), OR-butterfly, then
      readfirstlane back to SGPRs so the next chunk stays scalar. */
__global__ void __launch_bounds__(256) k_reduce_out(const u64* __restrict__ mask,
                                                    const int* __restrict__ order,
                                                    const float* __restrict__ tb,
                                                    const float* __restrict__ tscore,
                                                    const float* __restrict__ trans,
                                                    float* __restrict__ out) {
    __shared__ int keep_s[POST_NMS];
    if (threadIdx.x < 64) {
        const int lane = threadIdx.x;
        int cnt = 0;                                 /* uniform (SGPR) */
        u64 cur = 0;                                 /* uniform (SGPR) */
        u64 dwc = mask[(size_t)lane * MASK_W + 0];   /* chunk-0 diag words */
        for (int c = 0; c < MASK_W; ++c) {
            int nc = c + 1;
            u64 dwn = 0;
            if (nc < MASK_W) {
                int rn = nc * 64 + lane;
                if (rn < PRE_NMS) dwn = mask[(size_t)rn * MASK_W + nc];
            }
            int nrows = PRE_NMS - c * 64; if (nrows > 64) nrows = 64;
            u64 vm = (nrows >= 64) ? ~0ull : ((1ull << nrows) - 1ull);
            u32 dlo_v = (u32)dwc, dhi_v = (u32)(dwc >> 32);
            int cnt0 = cnt;
            u64 keptw = 0;
            u64 freeb = (~cur) & vm;
            while (freeb != 0ull && cnt < POST_NMS) {
                u32 bs;
                asm("s_ff1_i32_b64 %0, %1" : "=s"(bs) : "s"(freeb));
                u32 dlo, dhi;
                asm("v_readlane_b32 %0, %1, %2" : "=s"(dlo) : "v"(dlo_v), "s"(bs));
                asm("v_readlane_b32 %0, %1, %2" : "=s"(dhi) : "v"(dhi_v), "s"(bs));
                u64 bit = 1ull << bs;
                keptw |= bit;
                cur |= (((u64)dhi << 32) | (u64)dlo) | bit;
                cnt++;
                freeb = (~cur) & vm;
            }
            /* vector epilogue: scatter this chunk's keeps to keep_s */
            if ((keptw >> lane) & 1ull) {
                int pos = cnt0 + __popcll(keptw & ((1ull << lane) - 1ull));
                keep_s[pos] = c * 64 + lane;
            }
            if (cnt >= POST_NMS || nc >= MASK_W) break;
            /* transition: cur(next) = OR over all kept rows' mask word nc */
            u64 acc = 0;
#pragma unroll
            for (int s = 0; s < 5; ++s) {
                int p = s * 64 + lane;
                if (p < cnt) {
                    int kr = keep_s[p];
                    acc |= mask[(size_t)kr * MASK_W + nc];
                }
            }
#pragma unroll
            for (int m = 32; m >= 1; m >>= 1)
                acc |= (u64)__shfl_xor((unsigned long long)acc, m, 64);
            u32 clo = __builtin_amdgcn_readfirstlane((u32)acc);
            u32 chi = __builtin_amdgcn_readfirstlane((u32)(acc >> 32));
            cur = ((u64)chi << 32) | (u64)clo;
            dwc = dwn;
        }
        for (int r = cnt + lane; r < POST_NMS; r += 64) keep_s[r] = 0;
    }
    __syncthreads();
    for (int row = threadIdx.x; row < POST_NMS; row += 256) {
        int r = keep_s[row];
        int n = order[r];
        out[row * 5 + 0] = 0.0f;
        out[row * 5 + 1] = tb[r * 4 + 0];
        out[row * 5 + 2] = tb[r * 4 + 1];
        out[row * 5 + 3] = tb[r * 4 + 2];
        out[row * 5 + 4] = tb[r * 4 + 3];
        out[POST_NMS * 5 + row] = tscore[r];
        int hw = n / A_, a = n % A_;
        const float* tp = trans + (size_t)hw * (6 * A_) + a * 6;
#pragma unroll
        for (int c = 0; c < 6; ++c)
            out[POST_NMS * 6 + row * 6 + c] = tp[c];
    }
}

extern "C" void kernel_launch(void* const* d_in, const int* in_sizes, int n_in,
                              void* d_out, int out_size, void* d_ws, size_t ws_size,
                              hipStream_t stream) {
    const float* anchors = (const float*)d_in[0];
    const float* cls     = (const float*)d_in[1];
    const float* bbox    = (const float*)d_in[2];
    const float* trans   = (const float*)d_in[3];
    const float* im_info = (const float*)d_in[4];
    float* out = (float*)d_out;
    char* ws = (char*)d_ws;

    int*   hist   = (int*)(ws + OFF_HIST);
    int*   binCnt = (int*)(ws + OFF_BINCNT);
    int*   scal   = (int*)(ws + OFF_SCAL);
    int*   suf    = (int*)(ws + OFF_SUF);
    u64*   cand   = (u64*)(ws + OFF_CAND);
    int*   order  = (int*)(ws + OFF_ORDER);
    float* tscore = (float*)(ws + OFF_TSCORE);
    float* tb     = (float*)(ws + OFF_TBOX);
    u64*   mask   = (u64*)(ws + OFF_MASK);

    /* zero hist + binCnt + scal each call */
    hipMemsetAsync(ws + OFF_HIST, 0, OFF_SUF - OFF_HIST, stream);

    int nb = (N_ANCH + 255) / 256;
    k_hist<<<nb, 256, 0, stream>>>(cls, hist);
    k_scan<<<1, 256, 0, stream>>>(hist, suf, scal);
    k_compact<<<nb, 256, 0, stream>>>(cls, suf, scal, binCnt, cand);
    k_rank<<<CAND_CAP / 256, 256, 0, stream>>>(cand, hist, suf, scal,
                                               anchors, bbox, im_info,
                                               order, tscore, tb);
    dim3 mg(MASK_W, MASK_W);
    k_mask<<<mg, 64, 0, stream>>>(tb, mask);
    k_reduce_out<<<1, 256, 0, stream>>>(mask, order, tb, tscore, trans, out);
}